// Round 1
// baseline (704.916 us; speedup 1.0000x reference)
//
#include <hip/hip_runtime.h>
#include <hip/hip_bf16.h>
#include <stdint.h>

// FusedMoEBlock: router(sigmoid+top6) -> grouped SwiGLU expert FFN (scatter-add)
//                + shared SwiGLU FFN.
// Round 0: correctness-first bf16-MFMA pipeline.
//   T=2048 tokens, H=2048, E=64, I=512, IS=1024, top_k<=8 (6).
// d_out = [shared_out (T*H f32) | routed (T*H f32)].

#define H_DIM 2048
#define E_NUM 64
#define I_DIM 512
#define IS_DIM 1024
#define CAP 512          // max tokens per expert bucket (avg 192, ~24 sigma safe)
#define MT_MAX (CAP / 64)
#define TOPK_MAX 8

typedef float f32x4 __attribute__((ext_vector_type(4)));
typedef __bf16 bf16x8 __attribute__((ext_vector_type(8)));

__device__ __forceinline__ uint16_t f2bf(float f) {
  union { float f; uint32_t u; } v;
  v.f = f;
  uint32_t r = (v.u + 0x7FFFu + ((v.u >> 16) & 1u)) >> 16;  // RNE
  return (uint16_t)r;
}

// ---------------- x (f32) -> xb (bf16) ----------------
__global__ __launch_bounds__(256) void cvt_bf16(const float* __restrict__ in,
                                                uint16_t* __restrict__ out, int n8) {
  int i = blockIdx.x * 256 + threadIdx.x;
  if (i >= n8) return;
  const float4* p = (const float4*)in + (size_t)i * 2;
  float4 a = p[0], b = p[1];
  uint4 o;
  o.x = f2bf(a.x) | ((uint32_t)f2bf(a.y) << 16);
  o.y = f2bf(a.z) | ((uint32_t)f2bf(a.w) << 16);
  o.z = f2bf(b.x) | ((uint32_t)f2bf(b.y) << 16);
  o.w = f2bf(b.z) | ((uint32_t)f2bf(b.w) << 16);
  ((uint4*)out)[i] = o;
}

// ---------------- router: logits -> sigmoid -> top-k -> renorm -> buckets ----
// One block (4 waves) per token. Each wave computes 16 expert logits with
// coalesced gw reads; wave 0 does the top-k.
__global__ __launch_bounds__(256) void router_kernel(
    const float* __restrict__ x, const float* __restrict__ gw,
    const int* __restrict__ topk_ptr, int* __restrict__ cnt,
    int* __restrict__ bucket, float* __restrict__ bw) {
  const int t = blockIdx.x;
  const int tid = threadIdx.x;
  __shared__ float xs[H_DIM];
  __shared__ float logits[E_NUM];
#pragma unroll
  for (int i = 0; i < 2; ++i) {
    int idx = tid + i * 256;
    *(float4*)(&xs[idx * 4]) = *(const float4*)(x + (size_t)t * H_DIM + idx * 4);
  }
  __syncthreads();
  const int lane = tid & 63, wid = tid >> 6;
  float xr[32];
#pragma unroll
  for (int it = 0; it < 32; ++it) xr[it] = xs[lane + 64 * it];
  for (int eo = 0; eo < 16; ++eo) {
    int e = wid + eo * 4;
    const float* g = gw + (size_t)e * H_DIM;
    float acc = 0.f;
#pragma unroll
    for (int it = 0; it < 32; ++it) acc += xr[it] * g[lane + 64 * it];
#pragma unroll
    for (int off = 32; off; off >>= 1) acc += __shfl_xor(acc, off);
    if (lane == 0) logits[e] = acc;
  }
  __syncthreads();
  if (wid == 0) {
    int k = topk_ptr[0];
    if (k > TOPK_MAX) k = TOPK_MAX;
    // sigmoid; note: reference's pre-topk normalize is scale-invariant for both
    // selection and the final renormalized weights, so we skip it.
    float v = 1.f / (1.f + expf(-logits[lane]));
    float s = 0.f, myw = 0.f;
    int mye = 0;
    for (int j = 0; j < k; ++j) {
      float m = v;
      int mi = lane;
#pragma unroll
      for (int off = 32; off; off >>= 1) {
        float ov = __shfl_xor(m, off);
        int oi = __shfl_xor(mi, off);
        if (ov > m || (ov == m && oi < mi)) { m = ov; mi = oi; }
      }
      if (lane == j) { myw = m; mye = mi; }
      if (lane == mi) v = -1e30f;
      s += m;
    }
    if (lane < k) {
      float w = myw / s;
      int pos = atomicAdd(&cnt[mye], 1);
      if (pos < CAP) {
        bucket[mye * CAP + pos] = t;
        bw[mye * CAP + pos] = w;
      }
    }
  }
}

// ---------------- gate+up GEMM + silu*mul -> act (bf16) ----------------
// C[m,n] = X[m,:] @ W[:,n]; A rows gathered via bucket when GATHER.
// 64x64 tile, BK=32, 4 waves each computing a 32x32 quadrant via 16x16x32 MFMA.
// B tiles (f32 [K][N]) are converted to bf16 and stored K-transposed in LDS
// so fragment reads are contiguous ds_read_b128.
template <bool GATHER>
__global__ __launch_bounds__(256) void ffn_in(
    const uint16_t* __restrict__ xb, const float* __restrict__ Wg,
    const float* __restrict__ Wu, uint16_t* __restrict__ act,
    const int* __restrict__ cnt, const int* __restrict__ bucket,
    int K, int ldb, int Mtot) {
  const int e = blockIdx.z;
  const int mt = blockIdx.y, nt = blockIdx.x;
  int n_e;
  const float *Bg, *Bu;
  uint16_t* actE;
  if constexpr (GATHER) {
    n_e = cnt[e];
    n_e = n_e > CAP ? CAP : n_e;
    size_t wo = (size_t)e * K * ldb;
    Bg = Wg + wo;
    Bu = Wu + wo;
    actE = act + (size_t)e * CAP * ldb;  // act leading dim == ldb (== I_DIM)
  } else {
    n_e = Mtot;
    Bg = Wg;
    Bu = Wu;
    actE = act;  // leading dim == ldb (== IS_DIM)
  }
  if (mt * 64 >= n_e) return;

  __shared__ uint16_t As[64][40];   // [m][k], +8 pad -> 80B stride
  __shared__ uint16_t Bgs[64][40];  // [n][k] transposed
  __shared__ uint16_t Bus[64][40];

  const int tid = threadIdx.x;
  const int ar = tid >> 2, aseg = tid & 3;
  const int aslot = mt * 64 + ar;
  const bool avalid = aslot < n_e;
  const uint16_t* aptr;
  if constexpr (GATHER) {
    int tok = avalid ? bucket[e * CAP + aslot] : 0;
    aptr = xb + (size_t)tok * K;
  } else {
    aptr = xb + (size_t)aslot * K;
  }
  const int kp = tid & 15, c4 = tid >> 4;
  const float* bgp = Bg + (size_t)(2 * kp) * ldb + nt * 64 + c4 * 4;
  const float* bup = Bu + (size_t)(2 * kp) * ldb + nt * 64 + c4 * 4;

  const int lane = tid & 63, wid = tid >> 6;
  const int wm = wid >> 1, wn = wid & 1;
  const int fr = lane & 15, kg = lane >> 4;

  f32x4 accg[2][2] = {};
  f32x4 accu[2][2] = {};

  for (int k0 = 0; k0 < K; k0 += 32) {
    uint4 av = make_uint4(0, 0, 0, 0);
    if (avalid) av = *(const uint4*)(aptr + k0 + aseg * 8);
    const float* p0 = bgp + (size_t)k0 * ldb;
    float4 g0 = *(const float4*)p0;
    float4 g1 = *(const float4*)(p0 + ldb);
    const float* p1 = bup + (size_t)k0 * ldb;
    float4 u0 = *(const float4*)p1;
    float4 u1 = *(const float4*)(p1 + ldb);

    *(uint4*)(&As[ar][aseg * 8]) = av;
    *(uint32_t*)(&Bgs[c4 * 4 + 0][2 * kp]) = f2bf(g0.x) | ((uint32_t)f2bf(g1.x) << 16);
    *(uint32_t*)(&Bgs[c4 * 4 + 1][2 * kp]) = f2bf(g0.y) | ((uint32_t)f2bf(g1.y) << 16);
    *(uint32_t*)(&Bgs[c4 * 4 + 2][2 * kp]) = f2bf(g0.z) | ((uint32_t)f2bf(g1.z) << 16);
    *(uint32_t*)(&Bgs[c4 * 4 + 3][2 * kp]) = f2bf(g0.w) | ((uint32_t)f2bf(g1.w) << 16);
    *(uint32_t*)(&Bus[c4 * 4 + 0][2 * kp]) = f2bf(u0.x) | ((uint32_t)f2bf(u1.x) << 16);
    *(uint32_t*)(&Bus[c4 * 4 + 1][2 * kp]) = f2bf(u0.y) | ((uint32_t)f2bf(u1.y) << 16);
    *(uint32_t*)(&Bus[c4 * 4 + 2][2 * kp]) = f2bf(u0.z) | ((uint32_t)f2bf(u1.z) << 16);
    *(uint32_t*)(&Bus[c4 * 4 + 3][2 * kp]) = f2bf(u0.w) | ((uint32_t)f2bf(u1.w) << 16);
    __syncthreads();

    bf16x8 af[2], bgf[2], buf2[2];
#pragma unroll
    for (int mf = 0; mf < 2; ++mf)
      af[mf] = __builtin_bit_cast(
          bf16x8, *(const uint4*)(&As[wm * 32 + mf * 16 + fr][kg * 8]));
#pragma unroll
    for (int nf = 0; nf < 2; ++nf) {
      bgf[nf] = __builtin_bit_cast(
          bf16x8, *(const uint4*)(&Bgs[wn * 32 + nf * 16 + fr][kg * 8]));
      buf2[nf] = __builtin_bit_cast(
          bf16x8, *(const uint4*)(&Bus[wn * 32 + nf * 16 + fr][kg * 8]));
    }
#pragma unroll
    for (int mf = 0; mf < 2; ++mf)
#pragma unroll
      for (int nf = 0; nf < 2; ++nf) {
        accg[mf][nf] = __builtin_amdgcn_mfma_f32_16x16x32_bf16(
            af[mf], bgf[nf], accg[mf][nf], 0, 0, 0);
        accu[mf][nf] = __builtin_amdgcn_mfma_f32_16x16x32_bf16(
            af[mf], buf2[nf], accu[mf][nf], 0, 0, 0);
      }
    __syncthreads();
  }

  const int ncol0 = nt * 64;
#pragma unroll
  for (int mf = 0; mf < 2; ++mf)
#pragma unroll
    for (int nf = 0; nf < 2; ++nf)
#pragma unroll
      for (int rr = 0; rr < 4; ++rr) {
        int m = wm * 32 + mf * 16 + kg * 4 + rr;  // C/D: row=(lane>>4)*4+reg
        int slot = mt * 64 + m;
        if (slot < n_e) {
          int n = wn * 32 + nf * 16 + fr;  // C/D: col=lane&15
          float g = accg[mf][nf][rr], u = accu[mf][nf][rr];
          float a = g / (1.f + expf(-g)) * u;  // silu(g)*u
          actE[(size_t)slot * ldb + ncol0 + n] = f2bf(a);
        }
      }
}

// ---------------- down GEMM (+scale & scatter-add when SCATTER) -------------
template <bool SCATTER>
__global__ __launch_bounds__(256) void ffn_down(
    const uint16_t* __restrict__ act, const float* __restrict__ Wd,
    float* __restrict__ outp, const int* __restrict__ cnt,
    const int* __restrict__ bucket, const float* __restrict__ bw,
    int K, int Mtot) {
  const int e = blockIdx.z;
  const int mt = blockIdx.y, ht = blockIdx.x;
  int n_e;
  const uint16_t* actE;
  const float* Bd;
  if constexpr (SCATTER) {
    n_e = cnt[e];
    n_e = n_e > CAP ? CAP : n_e;
    actE = act + (size_t)e * CAP * K;
    Bd = Wd + (size_t)e * K * H_DIM;
  } else {
    n_e = Mtot;
    actE = act;
    Bd = Wd;
  }
  if (mt * 64 >= n_e) return;

  __shared__ uint16_t As[64][40];
  __shared__ uint16_t Bs[64][40];

  const int tid = threadIdx.x;
  const int ar = tid >> 2, aseg = tid & 3;
  const int aslot = mt * 64 + ar;
  const bool avalid = aslot < n_e;
  const uint16_t* aptr = actE + (size_t)aslot * K;

  const int kp = tid & 15, c4 = tid >> 4;
  const float* bdp = Bd + (size_t)(2 * kp) * H_DIM + ht * 64 + c4 * 4;

  const int lane = tid & 63, wid = tid >> 6;
  const int wm = wid >> 1, wn = wid & 1;
  const int fr = lane & 15, kg = lane >> 4;

  f32x4 acc[2][2] = {};

  for (int k0 = 0; k0 < K; k0 += 32) {
    uint4 av = make_uint4(0, 0, 0, 0);
    if (avalid) av = *(const uint4*)(aptr + k0 + aseg * 8);
    const float* p0 = bdp + (size_t)k0 * H_DIM;
    float4 d0 = *(const float4*)p0;
    float4 d1 = *(const float4*)(p0 + H_DIM);

    *(uint4*)(&As[ar][aseg * 8]) = av;
    *(uint32_t*)(&Bs[c4 * 4 + 0][2 * kp]) = f2bf(d0.x) | ((uint32_t)f2bf(d1.x) << 16);
    *(uint32_t*)(&Bs[c4 * 4 + 1][2 * kp]) = f2bf(d0.y) | ((uint32_t)f2bf(d1.y) << 16);
    *(uint32_t*)(&Bs[c4 * 4 + 2][2 * kp]) = f2bf(d0.z) | ((uint32_t)f2bf(d1.z) << 16);
    *(uint32_t*)(&Bs[c4 * 4 + 3][2 * kp]) = f2bf(d0.w) | ((uint32_t)f2bf(d1.w) << 16);
    __syncthreads();

    bf16x8 af[2], bf_[2];
#pragma unroll
    for (int mf = 0; mf < 2; ++mf)
      af[mf] = __builtin_bit_cast(
          bf16x8, *(const uint4*)(&As[wm * 32 + mf * 16 + fr][kg * 8]));
#pragma unroll
    for (int nf = 0; nf < 2; ++nf)
      bf_[nf] = __builtin_bit_cast(
          bf16x8, *(const uint4*)(&Bs[wn * 32 + nf * 16 + fr][kg * 8]));
#pragma unroll
    for (int mf = 0; mf < 2; ++mf)
#pragma unroll
      for (int nf = 0; nf < 2; ++nf)
        acc[mf][nf] = __builtin_amdgcn_mfma_f32_16x16x32_bf16(
            af[mf], bf_[nf], acc[mf][nf], 0, 0, 0);
    __syncthreads();
  }

#pragma unroll
  for (int mf = 0; mf < 2; ++mf)
#pragma unroll
    for (int nf = 0; nf < 2; ++nf)
#pragma unroll
      for (int rr = 0; rr < 4; ++rr) {
        int m = wm * 32 + mf * 16 + kg * 4 + rr;
        int slot = mt * 64 + m;
        int col = ht * 64 + wn * 32 + nf * 16 + fr;
        float yv = acc[mf][nf][rr];
        if constexpr (SCATTER) {
          if (slot < n_e) {
            int tok = bucket[e * CAP + slot];
            float w = bw[e * CAP + slot];
            atomicAdd(&outp[(size_t)tok * H_DIM + col], w * yv);
          }
        } else {
          outp[(size_t)slot * H_DIM + col] = yv;
        }
      }
}

extern "C" void kernel_launch(void* const* d_in, const int* in_sizes, int n_in,
                              void* d_out, int out_size, void* d_ws, size_t ws_size,
                              hipStream_t stream) {
  const float* x = (const float*)d_in[0];
  const float* gw = (const float*)d_in[1];
  const float* w_gate = (const float*)d_in[2];
  const float* w_up = (const float*)d_in[3];
  const float* w_down = (const float*)d_in[4];
  const float* sw_gate = (const float*)d_in[5];
  const float* sw_up = (const float*)d_in[6];
  const float* sw_down = (const float*)d_in[7];
  const int* topk = (const int*)d_in[8];
  const int T = in_sizes[0] / H_DIM;  // 2048

  float* shared_out = (float*)d_out;
  float* routed = shared_out + (size_t)T * H_DIM;

  char* ws = (char*)d_ws;
  size_t off = 0;
  auto take = [&](size_t b) {
    char* p = ws + off;
    off += (b + 255) & ~(size_t)255;
    return p;
  };
  uint16_t* xb = (uint16_t*)take((size_t)T * H_DIM * 2);           // 8.4 MB
  int* cnt = (int*)take(E_NUM * 4);
  int* bucket = (int*)take((size_t)E_NUM * CAP * 4);
  float* bw = (float*)take((size_t)E_NUM * CAP * 4);
  uint16_t* act = (uint16_t*)take((size_t)E_NUM * CAP * I_DIM * 2);  // 33.5 MB
  uint16_t* s_act = (uint16_t*)take((size_t)T * IS_DIM * 2);         // 4.2 MB

  hipMemsetAsync(cnt, 0, E_NUM * 4, stream);
  hipMemsetAsync(routed, 0, (size_t)T * H_DIM * 4, stream);

  int n8 = T * H_DIM / 8;
  cvt_bf16<<<(n8 + 255) / 256, 256, 0, stream>>>(x, xb, n8);
  router_kernel<<<T, 256, 0, stream>>>(x, gw, topk, cnt, bucket, bw);

  // grouped experts: gate+up -> act
  ffn_in<true><<<dim3(I_DIM / 64, MT_MAX, E_NUM), 256, 0, stream>>>(
      xb, w_gate, w_up, act, cnt, bucket, H_DIM, I_DIM, 0);
  // shared expert: gate+up -> s_act
  ffn_in<false><<<dim3(IS_DIM / 64, T / 64, 1), 256, 0, stream>>>(
      xb, sw_gate, sw_up, s_act, nullptr, nullptr, H_DIM, IS_DIM, T);
  // grouped experts: down, scaled scatter-add into routed
  ffn_down<true><<<dim3(H_DIM / 64, MT_MAX, E_NUM), 256, 0, stream>>>(
      act, w_down, routed, cnt, bucket, bw, I_DIM, 0);
  // shared expert: down -> shared_out
  ffn_down<false><<<dim3(H_DIM / 64, T / 64, 1), 256, 0, stream>>>(
      s_act, sw_down, shared_out, nullptr, nullptr, nullptr, IS_DIM, T);
}

// Round 2
// 569.410 us; speedup vs baseline: 1.2380x; 1.2380x over previous
//
#include <hip/hip_runtime.h>
#include <hip/hip_bf16.h>
#include <stdint.h>

// FusedMoEBlock R1: whole-expert tiles (BM=256), reg-prefetch pipeline,
// XCD-friendly grids. Weights (f32) streamed from HBM exactly once.
//   T=2048, H=2048, E=64, I=512, IS=1024, top_k<=8 (6).
// d_out = [shared_out (T*H f32) | routed (T*H f32)].

#define H_DIM 2048
#define E_NUM 64
#define I_DIM 512
#define IS_DIM 1024
#define CAP 512          // max tokens/expert (mean 192, max ~245 => 1 m-iter)
#define TOPK_MAX 8
#define BK 32

typedef float f32x4 __attribute__((ext_vector_type(4)));
typedef __bf16 bf16x8 __attribute__((ext_vector_type(8)));

__device__ __forceinline__ uint16_t f2bf(float f) {
  union { float f; uint32_t u; } v;
  v.f = f;
  uint32_t r = (v.u + 0x7FFFu + ((v.u >> 16) & 1u)) >> 16;  // RNE
  return (uint16_t)r;
}
__device__ __forceinline__ uint32_t pack2(float a, float b) {
  return (uint32_t)f2bf(a) | ((uint32_t)f2bf(b) << 16);
}

// ---------------- x (f32) -> xb (bf16) ----------------
__global__ __launch_bounds__(256) void cvt_bf16(const float* __restrict__ in,
                                                uint16_t* __restrict__ out, int n8) {
  int i = blockIdx.x * 256 + threadIdx.x;
  if (i >= n8) return;
  const float4* p = (const float4*)in + (size_t)i * 2;
  float4 a = p[0], b = p[1];
  uint4 o;
  o.x = pack2(a.x, a.y);
  o.y = pack2(a.z, a.w);
  o.z = pack2(b.x, b.y);
  o.w = pack2(b.z, b.w);
  ((uint4*)out)[i] = o;
}

// ---------------- router (unchanged from R0; fp32, passes) ----------------
__global__ __launch_bounds__(256) void router_kernel(
    const float* __restrict__ x, const float* __restrict__ gw,
    const int* __restrict__ topk_ptr, int* __restrict__ cnt,
    int* __restrict__ bucket, float* __restrict__ bw) {
  const int t = blockIdx.x;
  const int tid = threadIdx.x;
  __shared__ float xs[H_DIM];
  __shared__ float logits[E_NUM];
#pragma unroll
  for (int i = 0; i < 2; ++i) {
    int idx = tid + i * 256;
    *(float4*)(&xs[idx * 4]) = *(const float4*)(x + (size_t)t * H_DIM + idx * 4);
  }
  __syncthreads();
  const int lane = tid & 63, wid = tid >> 6;
  float xr[32];
#pragma unroll
  for (int it = 0; it < 32; ++it) xr[it] = xs[lane + 64 * it];
  for (int eo = 0; eo < 16; ++eo) {
    int e = wid + eo * 4;
    const float* g = gw + (size_t)e * H_DIM;
    float acc = 0.f;
#pragma unroll
    for (int it = 0; it < 32; ++it) acc += xr[it] * g[lane + 64 * it];
#pragma unroll
    for (int off = 32; off; off >>= 1) acc += __shfl_xor(acc, off);
    if (lane == 0) logits[e] = acc;
  }
  __syncthreads();
  if (wid == 0) {
    int k = topk_ptr[0];
    if (k > TOPK_MAX) k = TOPK_MAX;
    float v = 1.f / (1.f + expf(-logits[lane]));
    float s = 0.f, myw = 0.f;
    int mye = 0;
    for (int j = 0; j < k; ++j) {
      float m = v;
      int mi = lane;
#pragma unroll
      for (int off = 32; off; off >>= 1) {
        float ov = __shfl_xor(m, off);
        int oi = __shfl_xor(mi, off);
        if (ov > m || (ov == m && oi < mi)) { m = ov; mi = oi; }
      }
      if (lane == j) { myw = m; mye = mi; }
      if (lane == mi) v = -1e30f;
      s += m;
    }
    if (lane < k) {
      float w = myw / s;
      int pos = atomicAdd(&cnt[mye], 1);
      if (pos < CAP) {
        bucket[mye * CAP + pos] = t;
        bw[mye * CAP + pos] = w;
      }
    }
  }
}

// ---------------- gate+up GEMM + silu*mul -> act (bf16) ----------------
// THREADS=512 (gather): BM=256 BN=128, wave tile 64x64, grid (e, nt).
// THREADS=256 (dense):  BM=128 BN=64,  wave tile 64x32, grid (nt, mchunk).
// Reg-prefetch: next K-step's global loads issue before this step's MFMAs.
template <int THREADS_, bool GATHER>
__global__ __launch_bounds__(THREADS_, 2) void ffn_in(
    const uint16_t* __restrict__ xb, const float* __restrict__ Wg,
    const float* __restrict__ Wu, uint16_t* __restrict__ act,
    const int* __restrict__ cnt, const int* __restrict__ bucket,
    const int K, const int ldb) {
  constexpr int BM_ = THREADS_ / 2;
  constexpr int BN_ = THREADS_ / 4;
  constexpr int NF_ = BN_ / 32;   // B frags per wave
  constexpr int WTN = 16 * NF_;   // wave tile N

  int nt, mt0, mt1, n_e, e = 0;
  const float *Bg, *Bu;
  uint16_t* actE;
  if constexpr (GATHER) {
    e = blockIdx.x;  // x fastest -> same-e blocks share an XCD
    nt = blockIdx.y;
    n_e = cnt[e];
    n_e = n_e > CAP ? CAP : n_e;
    mt0 = 0;
    mt1 = (n_e + BM_ - 1) / BM_;
    const size_t wo = (size_t)e * K * ldb;
    Bg = Wg + wo;
    Bu = Wu + wo;
    actE = act + (size_t)e * CAP * ldb;
  } else {
    nt = blockIdx.x;  // x fastest -> same-nt blocks share an XCD
    mt0 = blockIdx.y;
    mt1 = mt0 + 1;
    n_e = gridDim.y * BM_;
    Bg = Wg;
    Bu = Wu;
    actE = act;
  }

  __shared__ uint16_t As[BM_][BK + 8];
  __shared__ uint16_t Bgs[BN_][BK + 8];
  __shared__ uint16_t Bus[BN_][BK + 8];

  const int tid = threadIdx.x;
  const int arow = tid >> 1, ahalf = (tid & 1) * 16;
  const int kp = (tid & 15) * 2, cg = (tid >> 4) * 4;
  const float* bgp = Bg + (size_t)kp * ldb + nt * BN_ + cg;
  const float* bup = Bu + (size_t)kp * ldb + nt * BN_ + cg;

  const int lane = tid & 63, wid = tid >> 6;
  const int wm = wid >> 1, wn = wid & 1;
  const int fr = lane & 15, kg = lane >> 4;

  for (int mt = mt0; mt < mt1; ++mt) {
    const int aslot = mt * BM_ + arow;
    bool avalid;
    const uint16_t* aptr;
    if constexpr (GATHER) {
      avalid = aslot < n_e;
      const int tok = avalid ? bucket[e * CAP + aslot] : 0;
      aptr = xb + (size_t)tok * K + ahalf;
    } else {
      avalid = true;
      aptr = xb + (size_t)aslot * K + ahalf;
    }

    f32x4 accg[4][NF_] = {};
    f32x4 accu[4][NF_] = {};

    uint4 a0 = make_uint4(0, 0, 0, 0), a1 = a0;
    if (avalid) {
      a0 = *(const uint4*)aptr;
      a1 = *(const uint4*)(aptr + 8);
    }
    float4 g0 = *(const float4*)bgp, g1 = *(const float4*)(bgp + ldb);
    float4 u0 = *(const float4*)bup, u1 = *(const float4*)(bup + ldb);

    for (int k0 = 0; k0 < K; k0 += BK) {
      __syncthreads();
      *(uint4*)(&As[arow][ahalf]) = a0;
      *(uint4*)(&As[arow][ahalf + 8]) = a1;
      *(uint32_t*)(&Bgs[cg + 0][kp]) = pack2(g0.x, g1.x);
      *(uint32_t*)(&Bgs[cg + 1][kp]) = pack2(g0.y, g1.y);
      *(uint32_t*)(&Bgs[cg + 2][kp]) = pack2(g0.z, g1.z);
      *(uint32_t*)(&Bgs[cg + 3][kp]) = pack2(g0.w, g1.w);
      *(uint32_t*)(&Bus[cg + 0][kp]) = pack2(u0.x, u1.x);
      *(uint32_t*)(&Bus[cg + 1][kp]) = pack2(u0.y, u1.y);
      *(uint32_t*)(&Bus[cg + 2][kp]) = pack2(u0.z, u1.z);
      *(uint32_t*)(&Bus[cg + 3][kp]) = pack2(u0.w, u1.w);
      __syncthreads();
      if (k0 + BK < K) {  // prefetch next step into regs (overlaps MFMA)
        if (avalid) {
          const uint16_t* ap = aptr + k0 + BK;
          a0 = *(const uint4*)ap;
          a1 = *(const uint4*)(ap + 8);
        }
        const float* bg = bgp + (size_t)(k0 + BK) * ldb;
        g0 = *(const float4*)bg;
        g1 = *(const float4*)(bg + ldb);
        const float* bu = bup + (size_t)(k0 + BK) * ldb;
        u0 = *(const float4*)bu;
        u1 = *(const float4*)(bu + ldb);
      }
      bf16x8 af[4], bgf[NF_], buf2[NF_];
#pragma unroll
      for (int mf = 0; mf < 4; ++mf)
        af[mf] = __builtin_bit_cast(
            bf16x8, *(const uint4*)(&As[wm * 64 + mf * 16 + fr][kg * 8]));
#pragma unroll
      for (int nf = 0; nf < NF_; ++nf) {
        bgf[nf] = __builtin_bit_cast(
            bf16x8, *(const uint4*)(&Bgs[wn * WTN + nf * 16 + fr][kg * 8]));
        buf2[nf] = __builtin_bit_cast(
            bf16x8, *(const uint4*)(&Bus[wn * WTN + nf * 16 + fr][kg * 8]));
      }
#pragma unroll
      for (int mf = 0; mf < 4; ++mf)
#pragma unroll
        for (int nf = 0; nf < NF_; ++nf) {
          accg[mf][nf] = __builtin_amdgcn_mfma_f32_16x16x32_bf16(
              af[mf], bgf[nf], accg[mf][nf], 0, 0, 0);
          accu[mf][nf] = __builtin_amdgcn_mfma_f32_16x16x32_bf16(
              af[mf], buf2[nf], accu[mf][nf], 0, 0, 0);
        }
    }

    const int col0 = nt * BN_ + wn * WTN;
#pragma unroll
    for (int mf = 0; mf < 4; ++mf)
#pragma unroll
      for (int nf = 0; nf < NF_; ++nf)
#pragma unroll
        for (int rr = 0; rr < 4; ++rr) {
          const int slot = mt * BM_ + wm * 64 + mf * 16 + kg * 4 + rr;
          if (slot < n_e) {
            const float g = accg[mf][nf][rr], u = accu[mf][nf][rr];
            const float a = g / (1.f + expf(-g)) * u;  // silu(g)*u
            actE[(size_t)slot * ldb + col0 + nf * 16 + fr] = f2bf(a);
          }
        }
  }
}

// ---------------- down GEMM (+scale & scatter-add when GATHER) --------------
template <int THREADS_, bool GATHER>
__global__ __launch_bounds__(THREADS_, 2) void ffn_down(
    const uint16_t* __restrict__ act, const float* __restrict__ Wd,
    float* __restrict__ outp, const int* __restrict__ cnt,
    const int* __restrict__ bucket, const float* __restrict__ bw,
    const int K) {
  constexpr int BM_ = THREADS_ / 2;
  constexpr int BN_ = THREADS_ / 4;
  constexpr int NF_ = BN_ / 32;
  constexpr int WTN = 16 * NF_;

  int nt, mt0, mt1, n_e, e = 0;
  const float* Bd;
  const uint16_t* actE;
  if constexpr (GATHER) {
    e = blockIdx.x;
    nt = blockIdx.y;
    n_e = cnt[e];
    n_e = n_e > CAP ? CAP : n_e;
    mt0 = 0;
    mt1 = (n_e + BM_ - 1) / BM_;
    actE = act + (size_t)e * CAP * K;
    Bd = Wd + (size_t)e * K * H_DIM;
  } else {
    nt = blockIdx.x;
    mt0 = blockIdx.y;
    mt1 = mt0 + 1;
    n_e = gridDim.y * BM_;
    actE = act;
    Bd = Wd;
  }

  __shared__ uint16_t As[BM_][BK + 8];
  __shared__ uint16_t Bs[BN_][BK + 8];

  const int tid = threadIdx.x;
  const int arow = tid >> 1, ahalf = (tid & 1) * 16;
  const int kp = (tid & 15) * 2, cg = (tid >> 4) * 4;
  const float* bdp = Bd + (size_t)kp * H_DIM + nt * BN_ + cg;

  const int lane = tid & 63, wid = tid >> 6;
  const int wm = wid >> 1, wn = wid & 1;
  const int fr = lane & 15, kg = lane >> 4;

  for (int mt = mt0; mt < mt1; ++mt) {
    const int aslot = mt * BM_ + arow;
    const bool avalid = aslot < n_e;
    const uint16_t* aptr = actE + (size_t)aslot * K + ahalf;

    f32x4 acc[4][NF_] = {};

    uint4 a0 = make_uint4(0, 0, 0, 0), a1 = a0;
    if (avalid) {
      a0 = *(const uint4*)aptr;
      a1 = *(const uint4*)(aptr + 8);
    }
    float4 d0 = *(const float4*)bdp, d1 = *(const float4*)(bdp + H_DIM);

    for (int k0 = 0; k0 < K; k0 += BK) {
      __syncthreads();
      *(uint4*)(&As[arow][ahalf]) = a0;
      *(uint4*)(&As[arow][ahalf + 8]) = a1;
      *(uint32_t*)(&Bs[cg + 0][kp]) = pack2(d0.x, d1.x);
      *(uint32_t*)(&Bs[cg + 1][kp]) = pack2(d0.y, d1.y);
      *(uint32_t*)(&Bs[cg + 2][kp]) = pack2(d0.z, d1.z);
      *(uint32_t*)(&Bs[cg + 3][kp]) = pack2(d0.w, d1.w);
      __syncthreads();
      if (k0 + BK < K) {
        if (avalid) {
          const uint16_t* ap = aptr + k0 + BK;
          a0 = *(const uint4*)ap;
          a1 = *(const uint4*)(ap + 8);
        }
        const float* bd = bdp + (size_t)(k0 + BK) * H_DIM;
        d0 = *(const float4*)bd;
        d1 = *(const float4*)(bd + H_DIM);
      }
      bf16x8 af[4], bf_[NF_];
#pragma unroll
      for (int mf = 0; mf < 4; ++mf)
        af[mf] = __builtin_bit_cast(
            bf16x8, *(const uint4*)(&As[wm * 64 + mf * 16 + fr][kg * 8]));
#pragma unroll
      for (int nf = 0; nf < NF_; ++nf)
        bf_[nf] = __builtin_bit_cast(
            bf16x8, *(const uint4*)(&Bs[wn * WTN + nf * 16 + fr][kg * 8]));
#pragma unroll
      for (int mf = 0; mf < 4; ++mf)
#pragma unroll
        for (int nf = 0; nf < NF_; ++nf)
          acc[mf][nf] = __builtin_amdgcn_mfma_f32_16x16x32_bf16(
              af[mf], bf_[nf], acc[mf][nf], 0, 0, 0);
    }

    const int col0 = nt * BN_ + wn * WTN;
#pragma unroll
    for (int mf = 0; mf < 4; ++mf)
#pragma unroll
      for (int nf = 0; nf < NF_; ++nf)
#pragma unroll
        for (int rr = 0; rr < 4; ++rr) {
          const int slot = mt * BM_ + wm * 64 + mf * 16 + kg * 4 + rr;
          const int col = col0 + nf * 16 + fr;
          const float yv = acc[mf][nf][rr];
          if constexpr (GATHER) {
            if (slot < n_e) {
              const int tok = bucket[e * CAP + slot];
              const float w = bw[e * CAP + slot];
              atomicAdd(&outp[(size_t)tok * H_DIM + col], w * yv);
            }
          } else {
            outp[(size_t)slot * H_DIM + col] = yv;
          }
        }
  }
}

extern "C" void kernel_launch(void* const* d_in, const int* in_sizes, int n_in,
                              void* d_out, int out_size, void* d_ws, size_t ws_size,
                              hipStream_t stream) {
  const float* x = (const float*)d_in[0];
  const float* gw = (const float*)d_in[1];
  const float* w_gate = (const float*)d_in[2];
  const float* w_up = (const float*)d_in[3];
  const float* w_down = (const float*)d_in[4];
  const float* sw_gate = (const float*)d_in[5];
  const float* sw_up = (const float*)d_in[6];
  const float* sw_down = (const float*)d_in[7];
  const int* topk = (const int*)d_in[8];
  const int T = in_sizes[0] / H_DIM;  // 2048

  float* shared_out = (float*)d_out;
  float* routed = shared_out + (size_t)T * H_DIM;

  char* ws = (char*)d_ws;
  size_t off = 0;
  auto take = [&](size_t b) {
    char* p = ws + off;
    off += (b + 255) & ~(size_t)255;
    return p;
  };
  uint16_t* xb = (uint16_t*)take((size_t)T * H_DIM * 2);             // 8.4 MB
  int* cnt = (int*)take(E_NUM * 4);
  int* bucket = (int*)take((size_t)E_NUM * CAP * 4);
  float* bw = (float*)take((size_t)E_NUM * CAP * 4);
  uint16_t* act = (uint16_t*)take((size_t)E_NUM * CAP * I_DIM * 2);  // 33.5 MB
  uint16_t* s_act = (uint16_t*)take((size_t)T * IS_DIM * 2);         // 4.2 MB

  hipMemsetAsync(cnt, 0, E_NUM * 4, stream);
  hipMemsetAsync(routed, 0, (size_t)T * H_DIM * 4, stream);

  int n8 = T * H_DIM / 8;
  cvt_bf16<<<(n8 + 255) / 256, 256, 0, stream>>>(x, xb, n8);
  router_kernel<<<T, 256, 0, stream>>>(x, gw, topk, cnt, bucket, bw);

  // grouped experts: gate+up -> act.  grid (e fastest, nt): e%8 ~ XCD
  ffn_in<512, true><<<dim3(E_NUM, I_DIM / 128), 512, 0, stream>>>(
      xb, w_gate, w_up, act, cnt, bucket, H_DIM, I_DIM);
  // shared expert: gate+up -> s_act.  grid (nt fastest, mchunk)
  ffn_in<256, false><<<dim3(IS_DIM / 64, T / 128), 256, 0, stream>>>(
      xb, sw_gate, sw_up, s_act, nullptr, nullptr, H_DIM, IS_DIM);
  // grouped experts: down, scaled scatter-add into routed
  ffn_down<512, true><<<dim3(E_NUM, H_DIM / 128), 512, 0, stream>>>(
      act, w_down, routed, cnt, bucket, bw, I_DIM);
  // shared expert: down -> shared_out
  ffn_down<256, false><<<dim3(H_DIM / 64, T / 128), 256, 0, stream>>>(
      s_act, sw_down, shared_out, nullptr, nullptr, nullptr, IS_DIM);
}

// Round 3
// 542.642 us; speedup vs baseline: 1.2990x; 1.0493x over previous
//
#include <hip/hip_runtime.h>
#include <hip/hip_bf16.h>
#include <stdint.h>

// FusedMoEBlock R2: atomic-free combine (ybuf + gather), 256-thr BK=64 GEMMs,
// router fused with bf16 conversion. T=2048,H=2048,E=64,I=512,IS=1024,k<=8.
// d_out = [shared_out (T*H f32) | routed (T*H f32)].

#define H_DIM 2048
#define E_NUM 64
#define I_DIM 512
#define IS_DIM 1024
#define CAP 512     // max tokens/expert (mean 192, ~max 240)
#define TOPK_MAX 8
#define BK 64
#define LDP 72      // LDS row stride in u16 (64 + 8 pad; 144B = 9x16B)

typedef float f32x4 __attribute__((ext_vector_type(4)));
typedef __bf16 bf16x8 __attribute__((ext_vector_type(8)));

__device__ __forceinline__ uint16_t f2bf(float f) {
  union { float f; uint32_t u; } v;
  v.f = f;
  uint32_t r = (v.u + 0x7FFFu + ((v.u >> 16) & 1u)) >> 16;  // RNE
  return (uint16_t)r;
}
__device__ __forceinline__ uint32_t pack2(float a, float b) {
  return (uint32_t)f2bf(a) | ((uint32_t)f2bf(b) << 16);
}
__device__ __forceinline__ float bf2f(uint16_t b) {
  union { uint32_t u; float f; } v;
  v.u = (uint32_t)b << 16;
  return v.f;
}

// ---------------- router: logits -> sigmoid -> top-k -> buckets; writes xb --
__global__ __launch_bounds__(256) void router_kernel(
    const float* __restrict__ x, const float* __restrict__ gw,
    const int* __restrict__ topk_ptr, int* __restrict__ cnt,
    int* __restrict__ bucket, float* __restrict__ bw,
    uint16_t* __restrict__ xb) {
  const int t = blockIdx.x;
  const int tid = threadIdx.x;
  __shared__ float xs[H_DIM];
  __shared__ float logits[E_NUM];
#pragma unroll
  for (int i = 0; i < 2; ++i) {
    int idx = tid + i * 256;
    *(float4*)(&xs[idx * 4]) = *(const float4*)(x + (size_t)t * H_DIM + idx * 4);
  }
  __syncthreads();
  {  // fused f32->bf16 conversion of this token's row
    const float* p = &xs[tid * 8];
    uint4 o;
    o.x = pack2(p[0], p[1]);
    o.y = pack2(p[2], p[3]);
    o.z = pack2(p[4], p[5]);
    o.w = pack2(p[6], p[7]);
    ((uint4*)(xb + (size_t)t * H_DIM))[tid] = o;
  }
  const int lane = tid & 63, wid = tid >> 6;
  float xr[32];
#pragma unroll
  for (int it = 0; it < 32; ++it) xr[it] = xs[lane + 64 * it];
  for (int eo = 0; eo < 16; ++eo) {
    int e = wid + eo * 4;
    const float* g = gw + (size_t)e * H_DIM;
    float acc = 0.f;
#pragma unroll
    for (int it = 0; it < 32; ++it) acc += xr[it] * g[lane + 64 * it];
#pragma unroll
    for (int off = 32; off; off >>= 1) acc += __shfl_xor(acc, off);
    if (lane == 0) logits[e] = acc;
  }
  __syncthreads();
  if (wid == 0) {
    int k = topk_ptr[0];
    if (k > TOPK_MAX) k = TOPK_MAX;
    // sigmoid; pre-topk normalize is scale-invariant -> skipped
    float v = 1.f / (1.f + expf(-logits[lane]));
    float s = 0.f, myw = 0.f;
    int mye = 0;
    for (int j = 0; j < k; ++j) {
      float m = v;
      int mi = lane;
#pragma unroll
      for (int off = 32; off; off >>= 1) {
        float ov = __shfl_xor(m, off);
        int oi = __shfl_xor(mi, off);
        if (ov > m || (ov == m && oi < mi)) { m = ov; mi = oi; }
      }
      if (lane == j) { myw = m; mye = mi; }
      if (lane == mi) v = -1e30f;
      s += m;
    }
    if (lane < k) {
      float w = myw / s;
      int pos = atomicAdd(&cnt[mye], 1);
      if (pos < CAP) {
        bucket[mye * CAP + pos] = t * 8 + lane;  // token*8 + choice slot
        bw[mye * CAP + pos] = w;
      }
    }
  }
}

// ---------------- gate+up GEMM + silu*mul -> act (bf16) ----------------
// 256 threads, 2x2 waves, BK=64. B (f32) converted+transposed into LDS.
template <int BM, int BN, bool GATHER>
__global__ __launch_bounds__(256) void ffn_in(
    const uint16_t* __restrict__ xb, const float* __restrict__ Wg,
    const float* __restrict__ Wu, uint16_t* __restrict__ act,
    const int* __restrict__ cnt, const int* __restrict__ bucket,
    const int K, const int ldb) {
  constexpr int MF = BM / 32, NF = BN / 32;
  constexpr int TPR = 256 / BM;        // threads per A row
  constexpr int A_VEC = 8 / TPR;       // uint4 loads per thread (A)
  constexpr int CG = BN / 4;           // B col groups
  constexpr int PG = 256 / CG;         // row-pairs per pass
  constexpr int PAIRS = (BK / 2) / PG;

  int e = 0, nt, mt0, mtE, n_e;
  const float *Bg, *Bu;
  uint16_t* actE;
  if constexpr (GATHER) {
    e = blockIdx.x;  // gridDim.x=64 (mult of 8) -> same-e blocks on one XCD
    nt = blockIdx.y;
    n_e = min(cnt[e], CAP);
    mt0 = 0;
    mtE = (n_e + BM - 1) / BM;
    const size_t wo = (size_t)e * K * ldb;
    Bg = Wg + wo;
    Bu = Wu + wo;
    actE = act + (size_t)e * CAP * ldb;
  } else {
    nt = blockIdx.x;  // same-nt (same B strip) blocks spread over y -> same XCD
    mt0 = blockIdx.y;
    mtE = mt0 + 1;
    n_e = gridDim.y * BM;
    Bg = Wg;
    Bu = Wu;
    actE = act;
  }
  if (mt0 * BM >= n_e) return;

  __shared__ uint16_t As[BM][LDP];
  __shared__ uint16_t Bgs[BN][LDP];
  __shared__ uint16_t Bus[BN][LDP];

  const int tid = threadIdx.x;
  const int arow = tid / TPR, aoff = (tid % TPR) * (BK / TPR);
  const int bcol = (tid % CG) * 4, brow = tid / CG;
  const float* bgp = Bg + (size_t)(2 * brow) * ldb + nt * BN + bcol;
  const float* bup = Bu + (size_t)(2 * brow) * ldb + nt * BN + bcol;

  const int lane = tid & 63, wid = tid >> 6;
  const int wm = wid >> 1, wn = wid & 1;
  const int fr = lane & 15, kg = lane >> 4;

  for (int mt = mt0; mt < mtE; ++mt) {
    const int aslot = mt * BM + arow;
    bool avalid;
    const uint16_t* aptr;
    if constexpr (GATHER) {
      avalid = aslot < n_e;
      const int bv = avalid ? bucket[e * CAP + aslot] : 0;
      aptr = xb + (size_t)(bv >> 3) * K + aoff;
    } else {
      avalid = true;
      aptr = xb + (size_t)aslot * K + aoff;
    }

    f32x4 accg[MF][NF] = {};
    f32x4 accu[MF][NF] = {};

    float4 g0[PAIRS], g1[PAIRS], u0[PAIRS], u1[PAIRS];
#pragma unroll
    for (int pp = 0; pp < PAIRS; ++pp) {  // initial B prefetch (k0=0)
      const float* g = bgp + (size_t)(2 * pp * PG) * ldb;
      g0[pp] = *(const float4*)g;
      g1[pp] = *(const float4*)(g + ldb);
      const float* u = bup + (size_t)(2 * pp * PG) * ldb;
      u0[pp] = *(const float4*)u;
      u1[pp] = *(const float4*)(u + ldb);
    }

    for (int k0 = 0; k0 < K; k0 += BK) {
      __syncthreads();
      // store B regs -> LDS (transposed, packed)
#pragma unroll
      for (int pp = 0; pp < PAIRS; ++pp) {
        const int rr2 = 2 * (brow + pp * PG);
        *(uint32_t*)(&Bgs[bcol + 0][rr2]) = pack2(g0[pp].x, g1[pp].x);
        *(uint32_t*)(&Bgs[bcol + 1][rr2]) = pack2(g0[pp].y, g1[pp].y);
        *(uint32_t*)(&Bgs[bcol + 2][rr2]) = pack2(g0[pp].z, g1[pp].z);
        *(uint32_t*)(&Bgs[bcol + 3][rr2]) = pack2(g0[pp].w, g1[pp].w);
        *(uint32_t*)(&Bus[bcol + 0][rr2]) = pack2(u0[pp].x, u1[pp].x);
        *(uint32_t*)(&Bus[bcol + 1][rr2]) = pack2(u0[pp].y, u1[pp].y);
        *(uint32_t*)(&Bus[bcol + 2][rr2]) = pack2(u0[pp].z, u1[pp].z);
        *(uint32_t*)(&Bus[bcol + 3][rr2]) = pack2(u0[pp].w, u1[pp].w);
      }
      // A tile (bf16, L2-resident): load + store this k-step
#pragma unroll
      for (int q = 0; q < A_VEC; ++q) {
        uint4 av = make_uint4(0, 0, 0, 0);
        if (avalid) av = *(const uint4*)(aptr + k0 + q * 8);
        *(uint4*)(&As[arow][aoff + q * 8]) = av;
      }
      __syncthreads();
      if (k0 + BK < K) {  // prefetch next B chunk (HBM stream, depth-1)
#pragma unroll
        for (int pp = 0; pp < PAIRS; ++pp) {
          const float* g = bgp + (size_t)(k0 + BK + 2 * pp * PG) * ldb;
          g0[pp] = *(const float4*)g;
          g1[pp] = *(const float4*)(g + ldb);
          const float* u = bup + (size_t)(k0 + BK + 2 * pp * PG) * ldb;
          u0[pp] = *(const float4*)u;
          u1[pp] = *(const float4*)(u + ldb);
        }
      }
#pragma unroll
      for (int kk = 0; kk < 2; ++kk) {
        bf16x8 af[MF];
#pragma unroll
        for (int mf = 0; mf < MF; ++mf)
          af[mf] = __builtin_bit_cast(
              bf16x8,
              *(const uint4*)(&As[wm * (BM / 2) + mf * 16 + fr][kg * 8 + kk * 32]));
#pragma unroll
        for (int nf = 0; nf < NF; ++nf) {
          bf16x8 bg = __builtin_bit_cast(
              bf16x8,
              *(const uint4*)(&Bgs[wn * (BN / 2) + nf * 16 + fr][kg * 8 + kk * 32]));
          bf16x8 bu = __builtin_bit_cast(
              bf16x8,
              *(const uint4*)(&Bus[wn * (BN / 2) + nf * 16 + fr][kg * 8 + kk * 32]));
#pragma unroll
          for (int mf = 0; mf < MF; ++mf) {
            accg[mf][nf] = __builtin_amdgcn_mfma_f32_16x16x32_bf16(
                af[mf], bg, accg[mf][nf], 0, 0, 0);
            accu[mf][nf] = __builtin_amdgcn_mfma_f32_16x16x32_bf16(
                af[mf], bu, accu[mf][nf], 0, 0, 0);
          }
        }
      }
    }

#pragma unroll
    for (int mf = 0; mf < MF; ++mf)
#pragma unroll
      for (int rr = 0; rr < 4; ++rr) {
        const int slot = mt * BM + wm * (BM / 2) + mf * 16 + kg * 4 + rr;
        if (slot < n_e) {
          const size_t ro = (size_t)slot * ldb + nt * BN + wn * (BN / 2) + fr;
#pragma unroll
          for (int nf = 0; nf < NF; ++nf) {
            const float g = accg[mf][nf][rr], u = accu[mf][nf][rr];
            actE[ro + nf * 16] = f2bf(g / (1.f + expf(-g)) * u);
          }
        }
      }
  }
}

// ---------------- down GEMM; GATHER -> weighted bf16 rows into ybuf ---------
template <int BM, int BN, bool GATHER>
__global__ __launch_bounds__(256) void ffn_down(
    const uint16_t* __restrict__ act, const float* __restrict__ Wd,
    void* __restrict__ outp, const int* __restrict__ cnt,
    const int* __restrict__ bucket, const float* __restrict__ bw, const int K) {
  constexpr int MF = BM / 32, NF = BN / 32;
  constexpr int TPR = 256 / BM;
  constexpr int A_VEC = 8 / TPR;
  constexpr int CG = BN / 4;
  constexpr int PG = 256 / CG;
  constexpr int PAIRS = (BK / 2) / PG;

  int e = 0, nt, mt0, mtE, n_e;
  const float* Bd;
  const uint16_t* actE;
  if constexpr (GATHER) {
    e = blockIdx.x;
    nt = blockIdx.y;
    n_e = min(cnt[e], CAP);
    mt0 = 0;
    mtE = (n_e + BM - 1) / BM;
    actE = act + (size_t)e * CAP * K;
    Bd = Wd + (size_t)e * K * H_DIM;
  } else {
    nt = blockIdx.x;
    mt0 = blockIdx.y;
    mtE = mt0 + 1;
    n_e = gridDim.y * BM;
    actE = act;
    Bd = Wd;
  }
  if (mt0 * BM >= n_e) return;

  __shared__ uint16_t As[BM][LDP];
  __shared__ uint16_t Bs[BN][LDP];

  const int tid = threadIdx.x;
  const int arow = tid / TPR, aoff = (tid % TPR) * (BK / TPR);
  const int bcol = (tid % CG) * 4, brow = tid / CG;
  const float* bdp = Bd + (size_t)(2 * brow) * H_DIM + nt * BN + bcol;

  const int lane = tid & 63, wid = tid >> 6;
  const int wm = wid >> 1, wn = wid & 1;
  const int fr = lane & 15, kg = lane >> 4;

  for (int mt = mt0; mt < mtE; ++mt) {
    const int aslot = mt * BM + arow;
    const bool avalid = aslot < n_e;
    const uint16_t* aptr = actE + (size_t)aslot * K + aoff;

    f32x4 acc[MF][NF] = {};

    float4 d0[PAIRS], d1[PAIRS];
#pragma unroll
    for (int pp = 0; pp < PAIRS; ++pp) {
      const float* d = bdp + (size_t)(2 * pp * PG) * H_DIM;
      d0[pp] = *(const float4*)d;
      d1[pp] = *(const float4*)(d + H_DIM);
    }

    for (int k0 = 0; k0 < K; k0 += BK) {
      __syncthreads();
#pragma unroll
      for (int pp = 0; pp < PAIRS; ++pp) {
        const int rr2 = 2 * (brow + pp * PG);
        *(uint32_t*)(&Bs[bcol + 0][rr2]) = pack2(d0[pp].x, d1[pp].x);
        *(uint32_t*)(&Bs[bcol + 1][rr2]) = pack2(d0[pp].y, d1[pp].y);
        *(uint32_t*)(&Bs[bcol + 2][rr2]) = pack2(d0[pp].z, d1[pp].z);
        *(uint32_t*)(&Bs[bcol + 3][rr2]) = pack2(d0[pp].w, d1[pp].w);
      }
#pragma unroll
      for (int q = 0; q < A_VEC; ++q) {
        uint4 av = make_uint4(0, 0, 0, 0);
        if (avalid) av = *(const uint4*)(aptr + k0 + q * 8);
        *(uint4*)(&As[arow][aoff + q * 8]) = av;
      }
      __syncthreads();
      if (k0 + BK < K) {
#pragma unroll
        for (int pp = 0; pp < PAIRS; ++pp) {
          const float* d = bdp + (size_t)(k0 + BK + 2 * pp * PG) * H_DIM;
          d0[pp] = *(const float4*)d;
          d1[pp] = *(const float4*)(d + H_DIM);
        }
      }
#pragma unroll
      for (int kk = 0; kk < 2; ++kk) {
        bf16x8 af[MF];
#pragma unroll
        for (int mf = 0; mf < MF; ++mf)
          af[mf] = __builtin_bit_cast(
              bf16x8,
              *(const uint4*)(&As[wm * (BM / 2) + mf * 16 + fr][kg * 8 + kk * 32]));
#pragma unroll
        for (int nf = 0; nf < NF; ++nf) {
          bf16x8 bf_ = __builtin_bit_cast(
              bf16x8,
              *(const uint4*)(&Bs[wn * (BN / 2) + nf * 16 + fr][kg * 8 + kk * 32]));
#pragma unroll
          for (int mf = 0; mf < MF; ++mf)
            acc[mf][nf] = __builtin_amdgcn_mfma_f32_16x16x32_bf16(
                af[mf], bf_, acc[mf][nf], 0, 0, 0);
        }
      }
    }

    const int col0 = nt * BN + wn * (BN / 2) + fr;
#pragma unroll
    for (int mf = 0; mf < MF; ++mf)
#pragma unroll
      for (int rr = 0; rr < 4; ++rr) {
        const int slot = mt * BM + wm * (BM / 2) + mf * 16 + kg * 4 + rr;
        if constexpr (GATHER) {
          if (slot < n_e) {
            const int bv = bucket[e * CAP + slot];
            const float w = bw[e * CAP + slot];
            uint16_t* yb = (uint16_t*)outp + (size_t)bv * H_DIM + col0;
#pragma unroll
            for (int nf = 0; nf < NF; ++nf)
              yb[nf * 16] = f2bf(w * acc[mf][nf][rr]);
          }
        } else {
          float* op = (float*)outp + (size_t)slot * H_DIM + col0;
#pragma unroll
          for (int nf = 0; nf < NF; ++nf) op[nf * 16] = acc[mf][nf][rr];
        }
      }
  }
}

// ---------------- combine: routed[t] = sum_j ybuf[t*8+j] ----------------
__global__ __launch_bounds__(256) void gather_kernel(
    const uint16_t* __restrict__ ybuf, const int* __restrict__ topk_ptr,
    float* __restrict__ routed) {
  const int t = blockIdx.x;
  const int tid = threadIdx.x;
  int k = topk_ptr[0];
  if (k > TOPK_MAX) k = TOPK_MAX;
  float acc[8] = {};
  const uint16_t* base = ybuf + (size_t)t * 8 * H_DIM + tid * 8;
  for (int j = 0; j < k; ++j) {
    uint4 v = *(const uint4*)(base + (size_t)j * H_DIM);
    const uint16_t* h = (const uint16_t*)&v;
#pragma unroll
    for (int i = 0; i < 8; ++i) acc[i] += bf2f(h[i]);
  }
  float4 o0 = make_float4(acc[0], acc[1], acc[2], acc[3]);
  float4 o1 = make_float4(acc[4], acc[5], acc[6], acc[7]);
  float* op = routed + (size_t)t * H_DIM + tid * 8;
  *(float4*)op = o0;
  *(float4*)(op + 4) = o1;
}

extern "C" void kernel_launch(void* const* d_in, const int* in_sizes, int n_in,
                              void* d_out, int out_size, void* d_ws, size_t ws_size,
                              hipStream_t stream) {
  const float* x = (const float*)d_in[0];
  const float* gw = (const float*)d_in[1];
  const float* w_gate = (const float*)d_in[2];
  const float* w_up = (const float*)d_in[3];
  const float* w_down = (const float*)d_in[4];
  const float* sw_gate = (const float*)d_in[5];
  const float* sw_up = (const float*)d_in[6];
  const float* sw_down = (const float*)d_in[7];
  const int* topk = (const int*)d_in[8];
  const int T = in_sizes[0] / H_DIM;  // 2048

  float* shared_out = (float*)d_out;
  float* routed = shared_out + (size_t)T * H_DIM;

  char* ws = (char*)d_ws;
  size_t off = 0;
  auto take = [&](size_t b) {
    char* p = ws + off;
    off += (b + 255) & ~(size_t)255;
    return p;
  };
  uint16_t* xb = (uint16_t*)take((size_t)T * H_DIM * 2);              // 8.4 MB
  int* cnt = (int*)take(E_NUM * 4);
  int* bucket = (int*)take((size_t)E_NUM * CAP * 4);
  float* bw = (float*)take((size_t)E_NUM * CAP * 4);
  uint16_t* act = (uint16_t*)take((size_t)E_NUM * CAP * I_DIM * 2);   // 33.5 MB
  uint16_t* s_act = (uint16_t*)take((size_t)T * IS_DIM * 2);          // 4.2 MB
  uint16_t* ybuf = (uint16_t*)take((size_t)T * 8 * H_DIM * 2);        // 67 MB

  hipMemsetAsync(cnt, 0, E_NUM * 4, stream);

  router_kernel<<<T, 256, 0, stream>>>(x, gw, topk, cnt, bucket, bw, xb);

  // grouped gate+up: tile 256x32, grid (e, nt); all same-e blocks on XCD e%8
  ffn_in<256, 32, true><<<dim3(E_NUM, I_DIM / 32), 256, 0, stream>>>(
      xb, w_gate, w_up, act, cnt, bucket, H_DIM, I_DIM);
  // shared gate+up: tile 64x64
  ffn_in<64, 64, false><<<dim3(IS_DIM / 64, T / 64), 256, 0, stream>>>(
      xb, sw_gate, sw_up, s_act, nullptr, nullptr, H_DIM, IS_DIM);
  // grouped down: tile 256x64 -> weighted bf16 rows in ybuf
  ffn_down<256, 64, true><<<dim3(E_NUM, H_DIM / 64), 256, 0, stream>>>(
      act, w_down, (void*)ybuf, cnt, bucket, bw, I_DIM);
  // shared down: tile 64x128 -> shared_out (f32)
  ffn_down<64, 128, false><<<dim3(H_DIM / 128, T / 64), 256, 0, stream>>>(
      s_act, sw_down, (void*)shared_out, nullptr, nullptr, nullptr, IS_DIM);
  // combine
  gather_kernel<<<T, 256, 0, stream>>>(ybuf, topk, routed);
}

// Round 4
// 506.818 us; speedup vs baseline: 1.3909x; 1.0707x over previous
//
#include <hip/hip_runtime.h>
#include <hip/hip_bf16.h>
#include <stdint.h>

// FusedMoEBlock R3: A-direct-from-L2 (no A LDS tile), BK=128, B-only LDS,
// 4-wave M-split so each A element is read once per block.
// T=2048,H=2048,E=64,I=512,IS=1024,k<=8.
// d_out = [shared_out (T*H f32) | routed (T*H f32)].

#define H_DIM 2048
#define E_NUM 64
#define I_DIM 512
#define IS_DIM 1024
#define CAP 512     // max tokens/expert (mean 192, max~245; 24 sigma)
#define TOPK_MAX 8
#define BK 128
#define LDP 136     // LDS row stride u16 (128+8; 272B = 17x16B, bank-adv 4)

typedef float f32x4 __attribute__((ext_vector_type(4)));
typedef __bf16 bf16x8 __attribute__((ext_vector_type(8)));

__device__ __forceinline__ uint16_t f2bf(float f) {
  union { float f; uint32_t u; } v;
  v.f = f;
  uint32_t r = (v.u + 0x7FFFu + ((v.u >> 16) & 1u)) >> 16;  // RNE
  return (uint16_t)r;
}
__device__ __forceinline__ uint32_t pack2(float a, float b) {
  return (uint32_t)f2bf(a) | ((uint32_t)f2bf(b) << 16);
}
__device__ __forceinline__ float bf2f(uint16_t b) {
  union { uint32_t u; float f; } v;
  v.u = (uint32_t)b << 16;
  return v.f;
}

// ---------------- router: logits -> sigmoid -> top-k -> buckets; writes xb --
__global__ __launch_bounds__(256) void router_kernel(
    const float* __restrict__ x, const float* __restrict__ gw,
    const int* __restrict__ topk_ptr, int* __restrict__ cnt,
    int* __restrict__ bucket, float* __restrict__ bw,
    uint16_t* __restrict__ xb) {
  const int t = blockIdx.x;
  const int tid = threadIdx.x;
  __shared__ float xs[H_DIM];
  __shared__ float logits[E_NUM];
#pragma unroll
  for (int i = 0; i < 2; ++i) {
    int idx = tid + i * 256;
    *(float4*)(&xs[idx * 4]) = *(const float4*)(x + (size_t)t * H_DIM + idx * 4);
  }
  __syncthreads();
  {  // fused f32->bf16 conversion of this token's row
    const float* p = &xs[tid * 8];
    uint4 o;
    o.x = pack2(p[0], p[1]);
    o.y = pack2(p[2], p[3]);
    o.z = pack2(p[4], p[5]);
    o.w = pack2(p[6], p[7]);
    ((uint4*)(xb + (size_t)t * H_DIM))[tid] = o;
  }
  const int lane = tid & 63, wid = tid >> 6;
  float xr[32];
#pragma unroll
  for (int it = 0; it < 32; ++it) xr[it] = xs[lane + 64 * it];
  for (int eo = 0; eo < 16; ++eo) {
    int e = wid + eo * 4;
    const float* g = gw + (size_t)e * H_DIM;
    float acc = 0.f;
#pragma unroll
    for (int it = 0; it < 32; ++it) acc += xr[it] * g[lane + 64 * it];
#pragma unroll
    for (int off = 32; off; off >>= 1) acc += __shfl_xor(acc, off);
    if (lane == 0) logits[e] = acc;
  }
  __syncthreads();
  if (wid == 0) {
    int k = topk_ptr[0];
    if (k > TOPK_MAX) k = TOPK_MAX;
    // sigmoid; pre-topk normalize is scale-invariant -> skipped
    float v = 1.f / (1.f + expf(-logits[lane]));
    float s = 0.f, myw = 0.f;
    int mye = 0;
    for (int j = 0; j < k; ++j) {
      float m = v;
      int mi = lane;
#pragma unroll
      for (int off = 32; off; off >>= 1) {
        float ov = __shfl_xor(m, off);
        int oi = __shfl_xor(mi, off);
        if (ov > m || (ov == m && oi < mi)) { m = ov; mi = oi; }
      }
      if (lane == j) { myw = m; mye = mi; }
      if (lane == mi) v = -1e30f;
      s += m;
    }
    if (lane < k) {
      float w = myw / s;
      int pos = atomicAdd(&cnt[mye], 1);
      if (pos < CAP) {
        bucket[mye * CAP + pos] = t * 8 + lane;  // token*8 + choice slot
        bw[mye * CAP + pos] = w;
      }
    }
  }
}

// ---------------- gate+up GEMM + silu*mul -> act (bf16) ----------------
// 4 waves, each owns BM/4 rows x all BN cols. A: per-lane 16B direct global
// reads (L2/L3-resident). B: f32 -> bf16 pack-transposed into LDS, depth-1
// reg prefetch of the next BK=128 chunk.
template <int BM, int BN, bool GATHER>
__global__ __launch_bounds__(256) void ffn_in(
    const uint16_t* __restrict__ xb, const float* __restrict__ Wg,
    const float* __restrict__ Wu, uint16_t* __restrict__ act,
    const int* __restrict__ cnt, const int* __restrict__ bucket,
    const int K, const int ldb) {
  constexpr int MF = BM / 64;          // 16-row frags per wave
  constexpr int NF = BN / 16;          // 16-col frags per wave (full BN)
  constexpr int CG = BN / 4;           // B col groups
  constexpr int PG = 256 / CG;         // k row-pairs per pass
  constexpr int PAIRS = (BK / 2) / PG;

  int e = 0, nt, mt0, mtE, n_e;
  const float *Bg, *Bu;
  uint16_t* actE;
  if constexpr (GATHER) {
    e = blockIdx.x;  // gridDim.x=64 -> all same-e blocks on XCD e%8
    nt = blockIdx.y;
    n_e = min(cnt[e], CAP);
    mt0 = 0;
    mtE = (n_e + BM - 1) / BM;
    const size_t wo = (size_t)e * K * ldb;
    Bg = Wg + wo;
    Bu = Wu + wo;
    actE = act + (size_t)e * CAP * ldb;
  } else {
    nt = blockIdx.x;  // same-strip blocks pinned to XCD nt%8
    mt0 = blockIdx.y;
    mtE = mt0 + 1;
    n_e = gridDim.y * BM;
    Bg = Wg;
    Bu = Wu;
    actE = act;
  }
  if (mt0 * BM >= n_e) return;

  __shared__ uint16_t Bgs[BN][LDP];
  __shared__ uint16_t Bus[BN][LDP];

  const int tid = threadIdx.x;
  const int bcol = (tid % CG) * 4, brow = tid / CG;
  const float* bgp = Bg + (size_t)(2 * brow) * ldb + nt * BN + bcol;
  const float* bup = Bu + (size_t)(2 * brow) * ldb + nt * BN + bcol;

  const int lane = tid & 63, wid = tid >> 6;
  const int fr = lane & 15, kg = lane >> 4;

  for (int mt = mt0; mt < mtE; ++mt) {
    // per-lane A row base pointers (gathered once per tile)
    const uint16_t* ab[MF];
#pragma unroll
    for (int mf = 0; mf < MF; ++mf) {
      const int slot = mt * BM + wid * (BM / 4) + mf * 16 + fr;
      if constexpr (GATHER) {
        const int idx = slot < n_e ? slot : 0;
        const int bv = bucket[e * CAP + idx];
        ab[mf] = xb + (size_t)(bv >> 3) * K + kg * 8;
      } else {
        ab[mf] = xb + (size_t)slot * K + kg * 8;
      }
    }

    f32x4 accg[MF][NF] = {};
    f32x4 accu[MF][NF] = {};

    float4 g0[PAIRS], g1[PAIRS], u0[PAIRS], u1[PAIRS];
#pragma unroll
    for (int pp = 0; pp < PAIRS; ++pp) {  // initial B prefetch (k0=0)
      const float* g = bgp + (size_t)(2 * pp * PG) * ldb;
      g0[pp] = *(const float4*)g;
      g1[pp] = *(const float4*)(g + ldb);
      const float* u = bup + (size_t)(2 * pp * PG) * ldb;
      u0[pp] = *(const float4*)u;
      u1[pp] = *(const float4*)(u + ldb);
    }

    for (int k0 = 0; k0 < K; k0 += BK) {
      __syncthreads();
#pragma unroll
      for (int pp = 0; pp < PAIRS; ++pp) {  // pack-transpose B -> LDS
        const int rr2 = 2 * (brow + pp * PG);
        *(uint32_t*)(&Bgs[bcol + 0][rr2]) = pack2(g0[pp].x, g1[pp].x);
        *(uint32_t*)(&Bgs[bcol + 1][rr2]) = pack2(g0[pp].y, g1[pp].y);
        *(uint32_t*)(&Bgs[bcol + 2][rr2]) = pack2(g0[pp].z, g1[pp].z);
        *(uint32_t*)(&Bgs[bcol + 3][rr2]) = pack2(g0[pp].w, g1[pp].w);
        *(uint32_t*)(&Bus[bcol + 0][rr2]) = pack2(u0[pp].x, u1[pp].x);
        *(uint32_t*)(&Bus[bcol + 1][rr2]) = pack2(u0[pp].y, u1[pp].y);
        *(uint32_t*)(&Bus[bcol + 2][rr2]) = pack2(u0[pp].z, u1[pp].z);
        *(uint32_t*)(&Bus[bcol + 3][rr2]) = pack2(u0[pp].w, u1[pp].w);
      }
      __syncthreads();
      if (k0 + BK < K) {  // prefetch next B chunk (overlaps MFMA phase)
#pragma unroll
        for (int pp = 0; pp < PAIRS; ++pp) {
          const float* g = bgp + (size_t)(k0 + BK + 2 * pp * PG) * ldb;
          g0[pp] = *(const float4*)g;
          g1[pp] = *(const float4*)(g + ldb);
          const float* u = bup + (size_t)(k0 + BK + 2 * pp * PG) * ldb;
          u0[pp] = *(const float4*)u;
          u1[pp] = *(const float4*)(u + ldb);
        }
      }
#pragma unroll
      for (int kk = 0; kk < BK / 32; ++kk) {
        bf16x8 af[MF];
#pragma unroll
        for (int mf = 0; mf < MF; ++mf)
          af[mf] = __builtin_bit_cast(
              bf16x8, *(const uint4*)(ab[mf] + k0 + kk * 32));
#pragma unroll
        for (int nf = 0; nf < NF; ++nf) {
          const bf16x8 bg = __builtin_bit_cast(
              bf16x8, *(const uint4*)(&Bgs[nf * 16 + fr][kg * 8 + kk * 32]));
          const bf16x8 bu = __builtin_bit_cast(
              bf16x8, *(const uint4*)(&Bus[nf * 16 + fr][kg * 8 + kk * 32]));
#pragma unroll
          for (int mf = 0; mf < MF; ++mf) {
            accg[mf][nf] = __builtin_amdgcn_mfma_f32_16x16x32_bf16(
                af[mf], bg, accg[mf][nf], 0, 0, 0);
            accu[mf][nf] = __builtin_amdgcn_mfma_f32_16x16x32_bf16(
                af[mf], bu, accu[mf][nf], 0, 0, 0);
          }
        }
      }
    }

#pragma unroll
    for (int mf = 0; mf < MF; ++mf)
#pragma unroll
      for (int rr = 0; rr < 4; ++rr) {
        const int slot = mt * BM + wid * (BM / 4) + mf * 16 + kg * 4 + rr;
        if (slot < n_e) {
          const size_t ro = (size_t)slot * ldb + nt * BN + fr;
#pragma unroll
          for (int nf = 0; nf < NF; ++nf) {
            const float g = accg[mf][nf][rr], u = accu[mf][nf][rr];
            actE[ro + nf * 16] = f2bf(g / (1.f + expf(-g)) * u);
          }
        }
      }
  }
}

// ---------------- down GEMM; GATHER -> weighted bf16 rows into ybuf ---------
template <int BM, int BN, bool GATHER>
__global__ __launch_bounds__(256) void ffn_down(
    const uint16_t* __restrict__ act, const float* __restrict__ Wd,
    void* __restrict__ outp, const int* __restrict__ cnt,
    const int* __restrict__ bucket, const float* __restrict__ bw, const int K) {
  constexpr int MF = BM / 64;
  constexpr int NF = BN / 16;
  constexpr int CG = BN / 4;
  constexpr int PG = 256 / CG;
  constexpr int PAIRS = (BK / 2) / PG;

  int e = 0, nt, mt0, mtE, n_e;
  const float* Bd;
  const uint16_t* actE;
  if constexpr (GATHER) {
    e = blockIdx.x;
    nt = blockIdx.y;
    n_e = min(cnt[e], CAP);
    mt0 = 0;
    mtE = (n_e + BM - 1) / BM;
    actE = act + (size_t)e * CAP * K;
    Bd = Wd + (size_t)e * K * H_DIM;
  } else {
    nt = blockIdx.x;
    mt0 = blockIdx.y;
    mtE = mt0 + 1;
    n_e = gridDim.y * BM;
    actE = act;
    Bd = Wd;
  }
  if (mt0 * BM >= n_e) return;

  __shared__ uint16_t Bs[BN][LDP];

  const int tid = threadIdx.x;
  const int bcol = (tid % CG) * 4, brow = tid / CG;
  const float* bdp = Bd + (size_t)(2 * brow) * H_DIM + nt * BN + bcol;

  const int lane = tid & 63, wid = tid >> 6;
  const int fr = lane & 15, kg = lane >> 4;

  for (int mt = mt0; mt < mtE; ++mt) {
    const uint16_t* ab[MF];
#pragma unroll
    for (int mf = 0; mf < MF; ++mf) {
      const int slot = mt * BM + wid * (BM / 4) + mf * 16 + fr;
      const int idx = slot < n_e ? slot : 0;
      ab[mf] = actE + (size_t)idx * K + kg * 8;
    }

    f32x4 acc[MF][NF] = {};

    float4 d0[PAIRS], d1[PAIRS];
#pragma unroll
    for (int pp = 0; pp < PAIRS; ++pp) {
      const float* d = bdp + (size_t)(2 * pp * PG) * H_DIM;
      d0[pp] = *(const float4*)d;
      d1[pp] = *(const float4*)(d + H_DIM);
    }

    for (int k0 = 0; k0 < K; k0 += BK) {
      __syncthreads();
#pragma unroll
      for (int pp = 0; pp < PAIRS; ++pp) {
        const int rr2 = 2 * (brow + pp * PG);
        *(uint32_t*)(&Bs[bcol + 0][rr2]) = pack2(d0[pp].x, d1[pp].x);
        *(uint32_t*)(&Bs[bcol + 1][rr2]) = pack2(d0[pp].y, d1[pp].y);
        *(uint32_t*)(&Bs[bcol + 2][rr2]) = pack2(d0[pp].z, d1[pp].z);
        *(uint32_t*)(&Bs[bcol + 3][rr2]) = pack2(d0[pp].w, d1[pp].w);
      }
      __syncthreads();
      if (k0 + BK < K) {
#pragma unroll
        for (int pp = 0; pp < PAIRS; ++pp) {
          const float* d = bdp + (size_t)(k0 + BK + 2 * pp * PG) * H_DIM;
          d0[pp] = *(const float4*)d;
          d1[pp] = *(const float4*)(d + H_DIM);
        }
      }
#pragma unroll
      for (int kk = 0; kk < BK / 32; ++kk) {
        bf16x8 af[MF];
#pragma unroll
        for (int mf = 0; mf < MF; ++mf)
          af[mf] = __builtin_bit_cast(
              bf16x8, *(const uint4*)(ab[mf] + k0 + kk * 32));
#pragma unroll
        for (int nf = 0; nf < NF; ++nf) {
          const bf16x8 bf_ = __builtin_bit_cast(
              bf16x8, *(const uint4*)(&Bs[nf * 16 + fr][kg * 8 + kk * 32]));
#pragma unroll
          for (int mf = 0; mf < MF; ++mf)
            acc[mf][nf] = __builtin_amdgcn_mfma_f32_16x16x32_bf16(
                af[mf], bf_, acc[mf][nf], 0, 0, 0);
        }
      }
    }

    const int col0 = nt * BN + fr;
#pragma unroll
    for (int mf = 0; mf < MF; ++mf)
#pragma unroll
      for (int rr = 0; rr < 4; ++rr) {
        const int slot = mt * BM + wid * (BM / 4) + mf * 16 + kg * 4 + rr;
        if constexpr (GATHER) {
          if (slot < n_e) {
            const int bv = bucket[e * CAP + slot];
            const float w = bw[e * CAP + slot];
            uint16_t* yb = (uint16_t*)outp + (size_t)bv * H_DIM + col0;
#pragma unroll
            for (int nf = 0; nf < NF; ++nf)
              yb[nf * 16] = f2bf(w * acc[mf][nf][rr]);
          }
        } else {
          float* op = (float*)outp + (size_t)slot * H_DIM + col0;
#pragma unroll
          for (int nf = 0; nf < NF; ++nf) op[nf * 16] = acc[mf][nf][rr];
        }
      }
  }
}

// ---------------- combine: routed[t] = sum_{j<k} ybuf[t*8+j] ----------------
__global__ __launch_bounds__(256) void gather_kernel(
    const uint16_t* __restrict__ ybuf, const int* __restrict__ topk_ptr,
    float* __restrict__ routed) {
  const int t = blockIdx.x;
  const int tid = threadIdx.x;
  int k = topk_ptr[0];
  if (k > TOPK_MAX) k = TOPK_MAX;
  float acc[8] = {};
  const uint16_t* base = ybuf + (size_t)t * 8 * H_DIM + tid * 8;
  for (int j = 0; j < k; ++j) {
    uint4 v = *(const uint4*)(base + (size_t)j * H_DIM);
    const uint16_t* h = (const uint16_t*)&v;
#pragma unroll
    for (int i = 0; i < 8; ++i) acc[i] += bf2f(h[i]);
  }
  float4 o0 = make_float4(acc[0], acc[1], acc[2], acc[3]);
  float4 o1 = make_float4(acc[4], acc[5], acc[6], acc[7]);
  float* op = routed + (size_t)t * H_DIM + tid * 8;
  *(float4*)op = o0;
  *(float4*)(op + 4) = o1;
}

extern "C" void kernel_launch(void* const* d_in, const int* in_sizes, int n_in,
                              void* d_out, int out_size, void* d_ws, size_t ws_size,
                              hipStream_t stream) {
  const float* x = (const float*)d_in[0];
  const float* gw = (const float*)d_in[1];
  const float* w_gate = (const float*)d_in[2];
  const float* w_up = (const float*)d_in[3];
  const float* w_down = (const float*)d_in[4];
  const float* sw_gate = (const float*)d_in[5];
  const float* sw_up = (const float*)d_in[6];
  const float* sw_down = (const float*)d_in[7];
  const int* topk = (const int*)d_in[8];
  const int T = in_sizes[0] / H_DIM;  // 2048

  float* shared_out = (float*)d_out;
  float* routed = shared_out + (size_t)T * H_DIM;

  char* ws = (char*)d_ws;
  size_t off = 0;
  auto take = [&](size_t b) {
    char* p = ws + off;
    off += (b + 255) & ~(size_t)255;
    return p;
  };
  uint16_t* xb = (uint16_t*)take((size_t)T * H_DIM * 2);              // 8.4 MB
  int* cnt = (int*)take(E_NUM * 4);
  int* bucket = (int*)take((size_t)E_NUM * CAP * 4);
  float* bw = (float*)take((size_t)E_NUM * CAP * 4);
  uint16_t* act = (uint16_t*)take((size_t)E_NUM * CAP * I_DIM * 2);   // 33.5 MB
  uint16_t* s_act = (uint16_t*)take((size_t)T * IS_DIM * 2);          // 4.2 MB
  uint16_t* ybuf = (uint16_t*)take((size_t)T * 8 * H_DIM * 2);        // 67 MB

  hipMemsetAsync(cnt, 0, E_NUM * 4, stream);

  router_kernel<<<T, 256, 0, stream>>>(x, gw, topk, cnt, bucket, bw, xb);

  // grouped gate+up: BM=256 BN=32, grid (e, nt)
  ffn_in<256, 32, true><<<dim3(E_NUM, I_DIM / 32), 256, 0, stream>>>(
      xb, w_gate, w_up, act, cnt, bucket, H_DIM, I_DIM);
  // grouped down: BM=256 BN=64 -> weighted bf16 rows in ybuf
  ffn_down<256, 64, true><<<dim3(E_NUM, H_DIM / 64), 256, 0, stream>>>(
      act, w_down, (void*)ybuf, cnt, bucket, bw, I_DIM);
  // combine routed
  gather_kernel<<<T, 256, 0, stream>>>(ybuf, topk, routed);
  // shared gate+up: BM=64 BN=64
  ffn_in<64, 64, false><<<dim3(IS_DIM / 64, T / 64), 256, 0, stream>>>(
      xb, sw_gate, sw_up, s_act, nullptr, nullptr, H_DIM, IS_DIM);
  // shared down: BM=64 BN=128 -> shared_out (f32)
  ffn_down<64, 128, false><<<dim3(H_DIM / 128, T / 64), 256, 0, stream>>>(
      s_act, sw_down, (void*)shared_out, nullptr, nullptr, nullptr, IS_DIM);
}